// Round 7
// baseline (51.059 us; speedup 1.0000x reference)
//
#include <hip/hip_runtime.h>

#define T_TOK 2048
#define AD    1024
#define HID   150
#define LW    10
#define NSTART (T_TOK - LW + 1)   // 2039
#define NSPAN  (NSTART * LW)      // 20390
#define RS    152                 // fp32 row stride for ws WT
#define FR    152                 // fp32 LDS row stride
#define PS    168                 // bf16 LDS row stride

// ws layout (floats): WT rows [0,16), then bf16 arena
#define OFF_WT   0
#define OFF_BF16 (16*RS)

#define SPB   16                  // starts per block
#define WIN   25                  // real window rows (SPB+9)

typedef __attribute__((ext_vector_type(8))) short bf16x8;
typedef __attribute__((ext_vector_type(4))) float f32x4;

__device__ inline unsigned short f2bf(float f) {
  unsigned u = __builtin_bit_cast(unsigned, f);
  u += 0x7fff + ((u >> 16) & 1);        // RNE
  return (unsigned short)(u >> 16);
}

__device__ inline unsigned cvt2(float lo, float hi) {   // packed bf16x2, RNE
  unsigned r;
  asm("v_cvt_pk_bf16_f32 %0, %1, %2" : "=v"(r) : "v"(lo), "v"(hi));
  return r;
}

// ---------------------------------------------------------------------------
// k_pack:
//   blocks [0,64):   W1 -> FRAGMENT-ORDER pack Wf: for n-tile nt(0..39),
//                    K-step ks(0..31), lane l=(g*16+r): 8 bf16 of
//                    W1col[nt*16+r][ks*32+g*8 ..+8]  (1KB/wave coalesced loads)
//   blocks [64,264): W2 pack-transpose -> W2t/AW2t [160][160] bf16
//   block  264:      WT width-bucket rows (fp32) -> ws
// ---------------------------------------------------------------------------
__global__ __launch_bounds__(256) void k_pack(
    const float* __restrict__ aw1, const float* __restrict__ sw1,
    const float* __restrict__ sw2, const float* __restrict__ aw2,
    const float* __restrict__ width_table, const float* __restrict__ score_b1,
    unsigned short* __restrict__ Wf,
    unsigned short* __restrict__ W2t, unsigned short* __restrict__ AW2t,
    float* __restrict__ ws) {
  __shared__ unsigned short T[152*72];    // 21.9 KB
  const int b = blockIdx.x, t = threadIdx.x;

  if (b < 64) {                         // ---- W1 frag pack: grp in [0,4), kt in [0,16)
    const int grp = b >> 4, kt = b & 15;
    const float* src = (grp == 0) ? aw1 : sw1 + (size_t)(grp-1)*AD*HID;
    const int k0 = kt * 64;
    for (int idx = t; idx < 64*152; idx += 256) {
      int kl = idx / 152, j = idx - kl*152;
      float v = (j < HID) ? src[(size_t)(k0+kl)*HID + j] : 0.f;
      T[j*72 + kl] = f2bf(v);
    }
    __syncthreads();
    for (int u = t; u < 160*8; u += 256) {
      int jj = u >> 3, kc = u & 7;
      bf16x8 v;
      if (jj < 152) v = *(const bf16x8*)&T[jj*72 + kc*8];
      else          v = (bf16x8){0,0,0,0,0,0,0,0};
      const int R  = grp*160 + jj;
      const int nt = R >> 4, r = R & 15;
      const int k  = k0 + kc*8;
      const int ks = k >> 5, g = (k >> 3) & 3;
      *(bf16x8*)&Wf[(size_t)(((nt*32 + ks)*64) + g*16 + r)*8] = v;
    }
  } else if (b < 264) {                 // ---- W2 packs (both MLPs)
    int idx = (b - 64) * 256 + t;       // 0..51199
    const float* src; unsigned short* dst; int u;
    if (idx < 25600) { src = sw2; dst = W2t; u = idx; }
    else             { src = aw2; dst = AW2t; u = idx - 25600; }
    int j = u / 160, k = u - j*160;
    float v = (j < HID && k < HID) ? src[(size_t)k*HID + j] : 0.f;
    dst[u] = f2bf(v);
  } else {                              // ---- WT width-bucket rows
    const int j = t;
    if (j < HID) {
      float* WT = ws + OFF_WT;
      for (int bb = 0; bb < 9; ++bb) {
        float acc = score_b1[j];
#pragma unroll
        for (int d = 0; d < 20; ++d)
          acc = fmaf(width_table[bb*20 + d], sw1[(size_t)(3*AD + d)*HID + j], acc);
        WT[bb*RS + j] = acc;
      }
    }
  }
}

// ---------------------------------------------------------------------------
// k_mega: one block = 16 starts (160 spans), window tokens i1b..i1b+24 (pad 32).
//   G1) stage states window -> aLDS bf16 (XOR swizzle); GEMM vs Wf n-tiles
//       {AH,SA,SB}; epilogue -> oAH(bf16)/oSA/oSB(fp32) LDS
//   G2) restage embeds window; GEMM n-tiles {EC} -> oEC
//   A) attn logits (MFMA vs AW2t on oAH)   B) prefix softmax
//   C) H1 build -> sH2 (region0, bf16)     D) layer-2 MFMA vs W2t -> out
// ---------------------------------------------------------------------------
#define A_OFF   0
#define AH_OFF  65536
#define SA_OFF  76288
#define SB_OFF  95744
#define EC_OFF  115200
#define WTL_OFF 134656
#define RED_OFF 138304
#define ATT_OFF 144704
#define E_OFF   144832
#define I_OFF   145472
#define LDS_SZ  146112

__global__ __launch_bounds__(640, 1) void k_mega(
    const unsigned short* __restrict__ Wf,
    const unsigned short* __restrict__ W2t,
    const unsigned short* __restrict__ AW2t,
    const float* __restrict__ st, const float* __restrict__ em,
    const float* __restrict__ ab1,
    const float* __restrict__ ab2, const float* __restrict__ aw3,
    const float* __restrict__ ab3,
    const float* __restrict__ sb2, const float* __restrict__ sw3,
    const float* __restrict__ sb3,
    const float* __restrict__ ws, float* __restrict__ out) {
  __shared__ __align__(16) char L[LDS_SZ];
  unsigned short* aL  = (unsigned short*)(L + A_OFF);   // [32][128 chunks][8]
  unsigned short* sH2 = (unsigned short*)(L + A_OFF);   // [160][PS] (reuses aL)
  unsigned short* oAH = (unsigned short*)(L + AH_OFF);  // [32][PS]
  float* oSA = (float*)(L + SA_OFF);                    // [32][FR]
  float* oSB = (float*)(L + SB_OFF);
  float* oEC = (float*)(L + EC_OFF);
  float* fWT = (float*)(L + WTL_OFF);                   // [6][FR]
  float* red = (float*)(L + RED_OFF);                   // [160][10]
  float* sATT = (float*)(L + ATT_OFF);                  // [32]
  float* sE = (float*)(L + E_OFF);                      // [16][10]
  float* sI = (float*)(L + I_OFF);

  const int i1b = blockIdx.x * SPB;
  const int t = threadIdx.x, lane = t & 63, w = t >> 6;
  const int r = lane & 15, g = lane >> 4;

  // ---- stage WT rows (1..5 used) and states panel
  if (t < 6*38) {
    int row = t / 38, c4 = t - row*38;
    *(float4*)&fWT[row*FR + c4*4] = *(const float4*)&ws[OFF_WT + row*RS + c4*4];
  }
  auto stageA = [&](const float* src) {
    for (int u = t; u < 32*128; u += 640) {
      int row = u >> 7, ch = u & 127;
      int tok = i1b + row;
      uint4 o;
      if (row < WIN && tok < T_TOK) {
        const float* gp = src + (size_t)tok*AD + ch*8;
        float4 a = *(const float4*)gp, c = *(const float4*)(gp + 4);
        o.x = cvt2(a.x, a.y); o.y = cvt2(a.z, a.w);
        o.z = cvt2(c.x, c.y); o.w = cvt2(c.z, c.w);
      } else o = (uint4){0,0,0,0};
      *(uint4*)&aL[(size_t)(row*128 + (ch ^ (row & 7)))*8] = o;
    }
  };
  stageA(st);
  __syncthreads();

  auto ldY = [&](int mt, int ks) {
    return *(const bf16x8*)&aL[(size_t)(((mt*16 + r)*128) + ((ks*4 + g) ^ (r & 7)))*8];
  };

  // ---- G1: n-tiles {w, 10+w, 20+w} = AH, SA, SB
  f32x4 a1[3][2];
#pragma unroll
  for (int j = 0; j < 3; ++j) { a1[j][0] = (f32x4){0,0,0,0}; a1[j][1] = (f32x4){0,0,0,0}; }
  {
    const unsigned short* xp[3];
#pragma unroll
    for (int j = 0; j < 3; ++j)
      xp[j] = Wf + (size_t)(((w + j*10)*32)*64 + lane)*8;
    bf16x8 X[3], Xn[3];
#pragma unroll
    for (int j = 0; j < 3; ++j) X[j] = *(const bf16x8*)xp[j];
    for (int ks = 0; ks < 32; ++ks) {
      if (ks < 31) {
#pragma unroll
        for (int j = 0; j < 3; ++j) Xn[j] = *(const bf16x8*)(xp[j] + (size_t)(ks+1)*512);
      }
      bf16x8 Y0 = ldY(0, ks), Y1 = ldY(1, ks);
#pragma unroll
      for (int j = 0; j < 3; ++j) {
        a1[j][0] = __builtin_amdgcn_mfma_f32_16x16x32_bf16(X[j], Y0, a1[j][0], 0, 0, 0);
        a1[j][1] = __builtin_amdgcn_mfma_f32_16x16x32_bf16(X[j], Y1, a1[j][1], 0, 0, 0);
      }
#pragma unroll
      for (int j = 0; j < 3; ++j) X[j] = Xn[j];
    }
  }
  __syncthreads();                 // all G1 reads of aL done
  stageA(em);                      // restage region0 with embeds
  {                                // epilogue G1 (registers -> LDS regions 1,2)
    const int jn = w*16 + g*4;
#pragma unroll
    for (int j = 0; j < 3; ++j)
#pragma unroll
      for (int mt = 0; mt < 2; ++mt) {
        f32x4 a = a1[j][mt];
        const int tokr = mt*16 + r;
        if (j == 0) {
#pragma unroll
          for (int q = 0; q < 4; ++q) {
            int jj = jn + q;
            float bb = (jj < HID) ? ab1[jj] : 0.f;
            oAH[tokr*PS + jj] = f2bf(fmaxf(a[q] + bb, 0.f));
          }
        } else {
          float* dst = (j == 1) ? oSA : oSB;
#pragma unroll
          for (int q = 0; q < 4; ++q) {
            int jj = jn + q;
            if (jj < FR) dst[tokr*FR + jj] = a[q];
          }
        }
      }
  }
  __syncthreads();

  // ---- G2: n-tile {30+w} = EC
  f32x4 a2[2]; a2[0] = (f32x4){0,0,0,0}; a2[1] = (f32x4){0,0,0,0};
  {
    const unsigned short* xp2 = Wf + (size_t)(((30 + w)*32)*64 + lane)*8;
    bf16x8 X2 = *(const bf16x8*)xp2, X2n;
    for (int ks = 0; ks < 32; ++ks) {
      if (ks < 31) X2n = *(const bf16x8*)(xp2 + (size_t)(ks+1)*512);
      bf16x8 Y0 = ldY(0, ks), Y1 = ldY(1, ks);
      a2[0] = __builtin_amdgcn_mfma_f32_16x16x32_bf16(X2, Y0, a2[0], 0, 0, 0);
      a2[1] = __builtin_amdgcn_mfma_f32_16x16x32_bf16(X2, Y1, a2[1], 0, 0, 0);
      X2 = X2n;
    }
    const int jn = w*16 + g*4;
#pragma unroll
    for (int mt = 0; mt < 2; ++mt) {
      const int tokr = mt*16 + r;
#pragma unroll
      for (int q = 0; q < 4; ++q) {
        int jj = jn + q;
        if (jj < FR) oEC[tokr*FR + jj] = a2[mt][q];
      }
    }
  }
  __syncthreads();

  // ---- Phase A: attn logits for window tokens (2 m-tiles)
  {
    f32x4 pa[2]; pa[0] = (f32x4){0,0,0,0}; pa[1] = (f32x4){0,0,0,0};
#pragma unroll
    for (int kc = 0; kc < 5; ++kc) {
      bf16x8 Af = *(const bf16x8*)&AW2t[(size_t)(w*16 + r)*160 + kc*32 + g*8];
#pragma unroll
      for (int mt = 0; mt < 2; ++mt) {
        bf16x8 Yf = *(const bf16x8*)&oAH[(mt*16 + r)*PS + kc*32 + g*8];
        pa[mt] = __builtin_amdgcn_mfma_f32_16x16x32_bf16(Af, Yf, pa[mt], 0, 0, 0);
      }
    }
    float b2v[4], w3v[4];
#pragma unroll
    for (int q = 0; q < 4; ++q) {
      int jj = w*16 + g*4 + q;
      b2v[q] = (jj < HID) ? ab2[jj] : 0.f;
      w3v[q] = (jj < HID) ? aw3[jj] : 0.f;
    }
#pragma unroll
    for (int mt = 0; mt < 2; ++mt) {
      float p = 0.f;
#pragma unroll
      for (int q = 0; q < 4; ++q)
        p += fmaxf(pa[mt][q] + b2v[q], 0.f) * w3v[q];
      p += __shfl_xor(p, 16);
      p += __shfl_xor(p, 32);
      if (g == 0) red[(mt*16 + r)*10 + w] = p;
    }
  }
  __syncthreads();
  if (t < 32) {
    float s = ab3[0];
#pragma unroll
    for (int q = 0; q < 10; ++q) s += red[t*10 + q];
    sATT[t] = s;
  }
  __syncthreads();

  // ---- Phase B: prefix softmax per start
  if (t < SPB) {
    int i1 = i1b + t;
    if (i1 < NSTART) {
      float a[10];
#pragma unroll
      for (int l = 0; l < 10; ++l) a[l] = sATT[t + l];
      float M = a[0];
#pragma unroll
      for (int l = 1; l < 10; ++l) M = fmaxf(M, a[l]);
      float D = 0.f;
#pragma unroll
      for (int l = 0; l < 10; ++l) {
        float e = expf(a[l] - M);
        D += e;
        sE[t*10 + l] = e;
        sI[t*10 + l] = 1.f / D;
      }
    } else {
#pragma unroll
      for (int l = 0; l < 10; ++l) { sE[t*10 + l] = 0.f; sI[t*10 + l] = 0.f; }
    }
  }
  __syncthreads();

  // ---- Phase C: build H1 (bf16) into region0
  const int binrow[10] = {1,2,3,4,4,4,4,5,5,5};
#pragma unroll
  for (int rep = 0; rep < 4; ++rep) {
    int u = rep*640 + t;                 // 0..2559 = 16 sl x 160 jj
    int sl = u / 160, jj = u - sl*160;
    if (jj < HID) {
      float sa = oSA[sl*FR + jj];
      float rs = 0.f;
#pragma unroll
      for (int l = 0; l < 10; ++l) {
        rs = fmaf(sE[sl*10 + l], oEC[(sl+l)*FR + jj], rs);
        float h = sa + oSB[(sl+l)*FR + jj] + fWT[binrow[l]*FR + jj]
                + rs * sI[sl*10 + l];
        sH2[(sl*10 + l)*PS + jj] = f2bf(fmaxf(h, 0.f));
      }
    } else {
#pragma unroll
      for (int l = 0; l < 10; ++l) sH2[(sl*10 + l)*PS + jj] = 0;
    }
  }
  __syncthreads();

  // ---- Phase D: layer-2 MFMA (10 m-tiles) + fused W3 reduce
  {
    bf16x8 Af[5];
#pragma unroll
    for (int kc = 0; kc < 5; ++kc)
      Af[kc] = *(const bf16x8*)&W2t[(size_t)(w*16 + r)*160 + kc*32 + g*8];
    f32x4 ac[10];
#pragma unroll
    for (int nt = 0; nt < 10; ++nt) ac[nt] = (f32x4){0,0,0,0};
#pragma unroll
    for (int nt = 0; nt < 10; ++nt)
#pragma unroll
      for (int kc = 0; kc < 5; ++kc) {
        bf16x8 Bf = *(const bf16x8*)&sH2[(nt*16 + r)*PS + kc*32 + g*8];
        ac[nt] = __builtin_amdgcn_mfma_f32_16x16x32_bf16(Af[kc], Bf, ac[nt], 0, 0, 0);
      }
    float b2v[4], w3v[4];
#pragma unroll
    for (int q = 0; q < 4; ++q) {
      int jj = w*16 + g*4 + q;
      b2v[q] = (jj < HID) ? sb2[jj] : 0.f;
      w3v[q] = (jj < HID) ? sw3[jj] : 0.f;
    }
#pragma unroll
    for (int nt = 0; nt < 10; ++nt) {
      float p = 0.f;
#pragma unroll
      for (int q = 0; q < 4; ++q)
        p += fmaxf(ac[nt][q] + b2v[q], 0.f) * w3v[q];
      p += __shfl_xor(p, 16);
      p += __shfl_xor(p, 32);
      if (g == 0) red[(nt*16 + r)*10 + w] = p;
    }
  }
  __syncthreads();
  if (t < 160) {
    int ng = i1b*10 + t;
    if (ng < NSPAN) {
      float s = sb3[0];
#pragma unroll
      for (int q = 0; q < 10; ++q) s += red[t*10 + q];
      out[ng] = s;
    }
  }
}

extern "C" void kernel_launch(void* const* d_in, const int* in_sizes, int n_in,
                              void* d_out, int out_size, void* d_ws, size_t ws_size,
                              hipStream_t stream) {
  const float* states      = (const float*)d_in[0];
  const float* embeds      = (const float*)d_in[1];
  const float* attn_W1     = (const float*)d_in[2];
  const float* attn_b1     = (const float*)d_in[3];
  const float* attn_W2     = (const float*)d_in[4];
  const float* attn_b2     = (const float*)d_in[5];
  const float* attn_W3     = (const float*)d_in[6];
  const float* attn_b3     = (const float*)d_in[7];
  const float* width_table = (const float*)d_in[8];
  const float* score_W1    = (const float*)d_in[9];
  const float* score_b1    = (const float*)d_in[10];
  const float* score_W2    = (const float*)d_in[11];
  const float* score_b2    = (const float*)d_in[12];
  const float* score_W3    = (const float*)d_in[13];
  const float* score_b3    = (const float*)d_in[14];
  float* out = (float*)d_out;
  float* ws  = (float*)d_ws;

  unsigned short* Wf   = (unsigned short*)(ws + OFF_BF16);   // 655360 shorts
  unsigned short* W2t  = Wf + 655360;
  unsigned short* AW2t = W2t + 25600;

  k_pack<<<265, 256, 0, stream>>>(attn_W1, score_W1, score_W2, attn_W2,
                                  width_table, score_b1, Wf, W2t, AW2t, ws);
  k_mega<<<(NSTART + SPB - 1)/SPB, 640, 0, stream>>>(Wf, W2t, AW2t,
                                  states, embeds, attn_b1,
                                  attn_b2, attn_W3, attn_b3,
                                  score_b2, score_W3, score_b3, ws, out);
}

// Round 8
// 43.020 us; speedup vs baseline: 1.1869x; 1.1869x over previous
//
#include <hip/hip_runtime.h>

#define T_TOK 2048
#define AD    1024
#define HID   150
#define LW    10
#define NSTART (T_TOK - LW + 1)   // 2039
#define NSPAN  (NSTART * LW)      // 20390
#define RS    152                 // padded fp32 row stride

// workspace offsets (in floats)
#define OFF_AH  0
#define OFF_SA  (OFF_AH + T_TOK*RS)
#define OFF_SB  (OFF_SA + T_TOK*RS)
#define OFF_EC  (OFF_SB + T_TOK*RS)
#define OFF_WT  (OFF_EC + T_TOK*RS)     // 16 rows reserved
#define OFF_ATT (OFF_WT + 16*RS)
#define OFF_BF16 (OFF_ATT + T_TOK)

typedef __attribute__((ext_vector_type(8))) short bf16x8;
typedef __attribute__((ext_vector_type(4))) float f32x4;

__device__ inline unsigned short f2bf(float f) {
  unsigned u = __builtin_bit_cast(unsigned, f);
  u += 0x7fff + ((u >> 16) & 1);        // RNE
  return (unsigned short)(u >> 16);
}

__device__ inline unsigned cvt2(float lo, float hi) {   // packed bf16x2, RNE
  unsigned r;
  asm("v_cvt_pk_bf16_f32 %0, %1, %2" : "=v"(r) : "v"(lo), "v"(hi));
  return r;
}

__device__ inline void gld16(const void* g, void* l) {
  __builtin_amdgcn_global_load_lds(
      (const __attribute__((address_space(1))) unsigned int*)g,
      (__attribute__((address_space(3))) unsigned int*)l, 16, 0, 0);
}

// ---------------------------------------------------------------------------
// k_pack: weight packing only.
// ---------------------------------------------------------------------------
__global__ __launch_bounds__(256) void k_pack(
    const float* __restrict__ aw1, const float* __restrict__ sw1,
    const float* __restrict__ sw2, const float* __restrict__ aw2,
    const float* __restrict__ width_table, const float* __restrict__ score_b1,
    unsigned short* __restrict__ Wt,
    unsigned short* __restrict__ W2t, unsigned short* __restrict__ AW2t,
    float* __restrict__ ws) {
  __shared__ unsigned short T[152*72];    // 21.9 KB
  const int b = blockIdx.x, t = threadIdx.x;

  if (b < 64) {                         // ---- W1 transpose
    const int grp = b >> 4, kt = b & 15;
    const float* src = (grp == 0) ? aw1 : sw1 + (size_t)(grp-1)*AD*HID;
    const int k0 = kt * 64;
    for (int idx = t; idx < 64*152; idx += 256) {
      int kl = idx / 152, j = idx - kl*152;
      float v = (j < HID) ? src[(size_t)(k0+kl)*HID + j] : 0.f;
      T[j*72 + kl] = f2bf(v);
    }
    __syncthreads();
    for (int u = t; u < 160*8; u += 256) {
      int jj = u >> 3, kc = u & 7;
      bf16x8 v;
      if (jj < 152) v = *(const bf16x8*)&T[jj*72 + kc*8];
      else          v = (bf16x8){0,0,0,0,0,0,0,0};
      *(bf16x8*)&Wt[(size_t)(grp*160 + jj)*AD + k0 + kc*8] = v;
    }
  } else if (b < 264) {                 // ---- W2 packs (both MLPs)
    int idx = (b - 64) * 256 + t;       // 0..51199
    const float* src; unsigned short* dst; int u;
    if (idx < 25600) { src = sw2; dst = W2t; u = idx; }
    else             { src = aw2; dst = AW2t; u = idx - 25600; }
    int j = u / 160, k = u - j*160;
    float v = (j < HID && k < HID) ? src[(size_t)k*HID + j] : 0.f;
    dst[u] = f2bf(v);
  } else {                              // ---- WT width-bucket rows
    const int j = t;
    if (j < HID) {
      float* WT = ws + OFF_WT;
      for (int bb = 0; bb < 9; ++bb) {
        float acc = score_b1[j];
#pragma unroll
        for (int d = 0; d < 20; ++d)
          acc = fmaf(width_table[bb*20 + d], sw1[(size_t)(3*AD + d)*HID + j], acc);
        WT[bb*RS + j] = acc;
      }
    }
  }
}

// ---------------------------------------------------------------------------
// k_gemm: layer-1 bf16 MFMA, fused fp32->bf16 on the A path.
//   Per K-step: loads issued -> MFMA on current buf -> cvt+ds_write
//   (vmcnt overlapped by MFMA phase) -> __syncthreads.
// ---------------------------------------------------------------------------
#define BM 32
#define KS 64
__global__ __launch_bounds__(320) void k_gemm(
    const float* __restrict__ st, const float* __restrict__ em,
    const unsigned short* __restrict__ Wt, const float* __restrict__ attn_b1,
    float* __restrict__ ws) {
  const int m0   = blockIdx.x * BM;
  const int s    = blockIdx.y >> 1;
  const int half = blockIdx.y & 1;
  const int tid  = threadIdx.x;
  const int lane = tid & 63, wv = tid >> 6;

  __shared__ unsigned short lA[2][BM*KS];   // 2 x 4KB
  __shared__ unsigned short lB[2][80*KS];   // 2 x 10KB

  const float* Ag = (s < 3 ? st : em) + (size_t)m0 * AD;
  const unsigned short* Bg = Wt + (size_t)(s*160 + half*80) * AD;

  f32x4 acc0 = {0.f,0.f,0.f,0.f}, acc1 = {0.f,0.f,0.f,0.f};

  const int arow = tid >> 3, ach = tid & 7;           // A chunk = tid (tid<256)
  const float* asrc = Ag + (size_t)arow*AD + ((ach ^ (arow & 7)) << 3);

  auto stageB = [&](int kb, int buf) {
    for (int seg = wv; seg < 10; seg += 5) {
      int c = seg*64 + lane;
      int row = c >> 3, ch = c & 7;
      gld16(Bg + (size_t)row*AD + kb + ((ch ^ (row & 7)) << 3), &lB[buf][seg*512]);
    }
  };

  const int r = lane & 15, g = lane >> 4;
  const int rx = wv*16 + r;
  const int sw = r & 7;

  float4 ra, rc;
  // prologue: tile 0
  if (tid < 256) { ra = *(const float4*)asrc; rc = *(const float4*)(asrc + 4); }
  stageB(0, 0);
  if (tid < 256) {
    uint4 o;
    o.x = cvt2(ra.x, ra.y); o.y = cvt2(ra.z, ra.w);
    o.z = cvt2(rc.x, rc.y); o.w = cvt2(rc.z, rc.w);
    *(uint4*)&lA[0][tid*8] = o;
  }
  __syncthreads();

  for (int kk = 0; kk < 16; ++kk) {
    const int buf = kk & 1;
    if (kk < 15) {
      const int kb = (kk+1)*KS;
      if (tid < 256) { ra = *(const float4*)(asrc + kb); rc = *(const float4*)(asrc + kb + 4); }
      stageB(kb, buf ^ 1);
    }
#pragma unroll
    for (int z = 0; z < 2; ++z) {
      const int cz = z*4 + g;
      bf16x8 X  = *(const bf16x8*)&lB[buf][rx*KS      + ((cz ^ sw) << 3)];
      bf16x8 Y0 = *(const bf16x8*)&lA[buf][r*KS       + ((cz ^ sw) << 3)];
      bf16x8 Y1 = *(const bf16x8*)&lA[buf][(16+r)*KS  + ((cz ^ sw) << 3)];
      acc0 = __builtin_amdgcn_mfma_f32_16x16x32_bf16(X, Y0, acc0, 0, 0, 0);
      acc1 = __builtin_amdgcn_mfma_f32_16x16x32_bf16(X, Y1, acc1, 0, 0, 0);
    }
    if (kk < 15 && tid < 256) {        // write-late: vmcnt wait overlapped by MFMAs
      uint4 o;
      o.x = cvt2(ra.x, ra.y); o.y = cvt2(ra.z, ra.w);
      o.z = cvt2(rc.x, rc.y); o.w = cvt2(rc.z, rc.w);
      *(uint4*)&lA[buf ^ 1][tid*8] = o;
    }
    __syncthreads();
  }

  const int jn = half*80 + wv*16 + g*4;
  float* Cp = ws + (s==0 ? OFF_AH : s==1 ? OFF_SA : s==2 ? OFF_SB : OFF_EC);
#pragma unroll
  for (int f = 0; f < 2; ++f) {
    int m = m0 + f*16 + r;
    f32x4 a = f ? acc1 : acc0;
    if (s == 0) {
#pragma unroll
      for (int q = 0; q < 4; ++q)
        if (jn + q < HID) a[q] = fmaxf(a[q] + attn_b1[jn+q], 0.f);
    }
    float* d = Cp + (size_t)m*RS + jn;
    if (jn + 3 < HID) *(f32x4*)d = a;
    else {
#pragma unroll
      for (int q = 0; q < 4; ++q) if (jn + q < HID) d[q] = a[q];
    }
  }
}

#define PS 168   // bf16 LDS row stride
#define FR 152   // fp32 LDS row stride (floats)

// ---------------------------------------------------------------------------
// k_span: per block of 8 starts (80 spans). All global inputs staged into LDS
// up front with coalesced loads; phases then run out of LDS.
// ---------------------------------------------------------------------------
#define SPB 8
__global__ __launch_bounds__(640) void k_span(
    const unsigned short* __restrict__ W2t,
    const unsigned short* __restrict__ AW2t,
    const float* __restrict__ ab2, const float* __restrict__ aw3,
    const float* __restrict__ ab3,
    const float* __restrict__ sb2, const float* __restrict__ sw3,
    const float* __restrict__ sb3,
    const float* __restrict__ ws, float* __restrict__ out) {
  const int i1b = blockIdx.x * SPB;
  const int t = threadIdx.x, lane = t & 63, wv = t >> 6;
  const int r = lane & 15, g = lane >> 4;
  __shared__ unsigned short sH[80 * PS];            // 26.9 KB
  __shared__ float fSB[17*FR], fEC[17*FR];          // 2 x 10.3 KB
  __shared__ float fSA[8*FR],  fWT[6*FR];           // 4.9 + 3.6 KB
  __shared__ float red[80][10];
  __shared__ float sATT[32];
  __shared__ float sE[SPB][10], sI[SPB][10];
  const float* AH  = ws + OFF_AH;
  const float* SA  = ws + OFF_SA;
  const float* SBp = ws + OFF_SB;
  const float* EC  = ws + OFF_EC;
  const float* WT  = ws + OFF_WT;

  // ---- Stage: AH window -> sH (bf16), SB/EC/SA/WT windows -> fp32 LDS.
  for (int u = t; u < 32*160; u += 640) {
    int row = u / 160, jj = u - row*160;
    int tok = i1b + row;
    float v = (row < 17 && jj < HID && tok < T_TOK) ? AH[(size_t)tok*RS + jj] : 0.f;
    sH[row*PS + jj] = f2bf(v);
  }
  // 48 rows x 38 float4 = 1824 float4 loads, coalesced.
  for (int u = t; u < 48*38; u += 640) {
    int row = u / 38, c4 = u - row*38;
    const float* gsrc; float* ldst;
    if (row < 17)      { gsrc = SBp + (size_t)(i1b+row)*RS;    ldst = fSB + row*FR; }
    else if (row < 34) { gsrc = EC  + (size_t)(i1b+row-17)*RS; ldst = fEC + (row-17)*FR; }
    else if (row < 42) { gsrc = SA  + (size_t)(i1b+row-34)*RS; ldst = fSA + (row-34)*FR; }
    else               { gsrc = WT  + (size_t)(row-42)*RS;     ldst = fWT + (row-42)*FR; }
    *(float4*)(ldst + c4*4) = *(const float4*)(gsrc + c4*4);
  }
  __syncthreads();

  // ---- Phase A: attention logits for tokens i1b..i1b+16
  {
    const int jt = wv;
    bf16x8 Af[5];
#pragma unroll
    for (int kc = 0; kc < 5; ++kc)
      Af[kc] = *(const bf16x8*)&AW2t[(size_t)(jt*16 + r)*160 + kc*32 + g*8];
    f32x4 acc[2];
#pragma unroll
    for (int nt = 0; nt < 2; ++nt) acc[nt] = (f32x4){0.f,0.f,0.f,0.f};
#pragma unroll
    for (int nt = 0; nt < 2; ++nt)
#pragma unroll
      for (int kc = 0; kc < 5; ++kc) {
        bf16x8 Bf = *(const bf16x8*)&sH[(nt*16 + r)*PS + kc*32 + g*8];
        acc[nt] = __builtin_amdgcn_mfma_f32_16x16x32_bf16(Af[kc], Bf, acc[nt], 0, 0, 0);
      }
    float b2v[4], w3v[4];
#pragma unroll
    for (int q = 0; q < 4; ++q) {
      int j = jt*16 + g*4 + q;
      b2v[q] = (j < HID) ? ab2[j] : 0.f;
      w3v[q] = (j < HID) ? aw3[j] : 0.f;
    }
#pragma unroll
    for (int nt = 0; nt < 2; ++nt) {
      float p = 0.f;
#pragma unroll
      for (int q = 0; q < 4; ++q)
        p += fmaxf(acc[nt][q] + b2v[q], 0.f) * w3v[q];
      p += __shfl_xor(p, 16);
      p += __shfl_xor(p, 32);
      if (g == 0) red[nt*16 + r][wv] = p;
    }
  }
  __syncthreads();
  if (t < 32) {
    float s = ab3[0];
#pragma unroll
    for (int w = 0; w < 10; ++w) s += red[t][w];
    sATT[t] = s;
  }
  __syncthreads();

  // ---- Phase B: prefix softmax per start
  if (t < SPB) {
    int i1 = i1b + t;
    if (i1 < NSTART) {
      float a[10];
#pragma unroll
      for (int l = 0; l < 10; ++l) a[l] = sATT[t + l];
      float M = a[0];
#pragma unroll
      for (int l = 1; l < 10; ++l) M = fmaxf(M, a[l]);
      float D = 0.f;
#pragma unroll
      for (int l = 0; l < 10; ++l) {
        float e = expf(a[l] - M);
        D += e;
        sE[t][l] = e;
        sI[t][l] = 1.f / D;
      }
    } else {
#pragma unroll
      for (int l = 0; l < 10; ++l) { sE[t][l] = 0.f; sI[t][l] = 0.f; }
    }
  }
  __syncthreads();

  // ---- Phase C: build H1 (bf16) in LDS from staged windows
  const int binrow[10] = {1,2,3,4,4,4,4,5,5,5};
#pragma unroll
  for (int rep = 0; rep < 2; ++rep) {
    int u = rep*640 + t;                 // 0..1279
    int sl = u / 160, jj = u - sl*160;
    if (jj < HID) {
      float sa = fSA[sl*FR + jj];
      float rs = 0.f;
#pragma unroll
      for (int l = 0; l < 10; ++l) {
        rs = fmaf(sE[sl][l], fEC[(sl+l)*FR + jj], rs);
        float h = sa + fSB[(sl+l)*FR + jj] + fWT[binrow[l]*FR + jj]
                + rs * sI[sl][l];
        sH[(sl*10 + l)*PS + jj] = f2bf(fmaxf(h, 0.f));
      }
    } else {
#pragma unroll
      for (int l = 0; l < 10; ++l) sH[(sl*10 + l)*PS + jj] = 0;
    }
  }
  __syncthreads();

  // ---- Phase D: layer-2 MFMA + fused W3 reduce
  const int jt = wv;
  bf16x8 Af[5];
#pragma unroll
  for (int kc = 0; kc < 5; ++kc)
    Af[kc] = *(const bf16x8*)&W2t[(size_t)(jt*16 + r)*160 + kc*32 + g*8];
  f32x4 acc[5];
#pragma unroll
  for (int nt = 0; nt < 5; ++nt) acc[nt] = (f32x4){0.f,0.f,0.f,0.f};
#pragma unroll
  for (int nt = 0; nt < 5; ++nt)
#pragma unroll
    for (int kc = 0; kc < 5; ++kc) {
      bf16x8 Bf = *(const bf16x8*)&sH[(nt*16 + r)*PS + kc*32 + g*8];
      acc[nt] = __builtin_amdgcn_mfma_f32_16x16x32_bf16(Af[kc], Bf, acc[nt], 0, 0, 0);
    }

  float b2v[4], w3v[4];
#pragma unroll
  for (int q = 0; q < 4; ++q) {
    int j = jt*16 + g*4 + q;
    b2v[q] = (j < HID) ? sb2[j] : 0.f;
    w3v[q] = (j < HID) ? sw3[j] : 0.f;
  }
#pragma unroll
  for (int nt = 0; nt < 5; ++nt) {
    float p = 0.f;
#pragma unroll
    for (int q = 0; q < 4; ++q)
      p += fmaxf(acc[nt][q] + b2v[q], 0.f) * w3v[q];
    p += __shfl_xor(p, 16);
    p += __shfl_xor(p, 32);
    if (g == 0) red[nt*16 + r][wv] = p;
  }
  __syncthreads();
  if (t < 80) {
    int ng = i1b*10 + t;
    if (ng < NSPAN) {
      float s = sb3[0];
#pragma unroll
      for (int w = 0; w < 10; ++w) s += red[t][w];
      out[ng] = s;
    }
  }
}

extern "C" void kernel_launch(void* const* d_in, const int* in_sizes, int n_in,
                              void* d_out, int out_size, void* d_ws, size_t ws_size,
                              hipStream_t stream) {
  const float* states      = (const float*)d_in[0];
  const float* embeds      = (const float*)d_in[1];
  const float* attn_W1     = (const float*)d_in[2];
  const float* attn_b1     = (const float*)d_in[3];
  const float* attn_W2     = (const float*)d_in[4];
  const float* attn_b2     = (const float*)d_in[5];
  const float* attn_W3     = (const float*)d_in[6];
  const float* attn_b3     = (const float*)d_in[7];
  const float* width_table = (const float*)d_in[8];
  const float* score_W1    = (const float*)d_in[9];
  const float* score_b1    = (const float*)d_in[10];
  const float* score_W2    = (const float*)d_in[11];
  const float* score_b2    = (const float*)d_in[12];
  const float* score_W3    = (const float*)d_in[13];
  const float* score_b3    = (const float*)d_in[14];
  float* out = (float*)d_out;
  float* ws  = (float*)d_ws;

  unsigned short* Wt   = (unsigned short*)(ws + OFF_BF16);
  unsigned short* W2t  = Wt + 640*AD;
  unsigned short* AW2t = W2t + 25600;

  k_pack<<<265, 256, 0, stream>>>(attn_W1, score_W1, score_W2, attn_W2,
                                  width_table, score_b1, Wt, W2t, AW2t, ws);
  k_gemm<<<dim3(T_TOK/BM, 8), 320, 0, stream>>>(states, embeds, Wt, attn_b1, ws);
  k_span<<<(NSTART+SPB-1)/SPB, 640, 0, stream>>>(W2t, AW2t,
                                  attn_b2, attn_W3, attn_b3,
                                  score_b2, score_W3, score_b3, ws, out);
}